// Round 8
// baseline (284.012 us; speedup 1.0000x reference)
//
#include <hip/hip_runtime.h>
#include <math.h>

// Problem geometry (fixed by the reference)
#define BB 8
#define CC 256
#define HWSZ 36864            // floats per (b,c) slice
#define TPB 256
#define IT 36                 // float4 per thread per slice (36*256*4 = 36864)
#define INTERNAL 16
#define NSLICE 2048
#define NBLK 1024             // each block owns slices blk and blk+1024

typedef float f4 __attribute__((ext_vector_type(4)));

// ---------------- helpers ----------------
__device__ __forceinline__ float slice_sumsq(const float* __restrict__ in,
                                             int s, int tid)
{
    const f4* p = reinterpret_cast<const f4*>(in + (size_t)s * HWSZ);
    float a0 = 0.f, a1 = 0.f, a2 = 0.f, a3 = 0.f;
    #pragma unroll
    for (int i = 0; i < IT; i += 4) {
        f4 v0 = p[tid + (i + 0) * TPB];   // caching loads: want L3 residency
        f4 v1 = p[tid + (i + 1) * TPB];
        f4 v2 = p[tid + (i + 2) * TPB];
        f4 v3 = p[tid + (i + 3) * TPB];
        a0 += v0.x * v0.x + v0.y * v0.y + v0.z * v0.z + v0.w * v0.w;
        a1 += v1.x * v1.x + v1.y * v1.y + v1.z * v1.z + v1.w * v1.w;
        a2 += v2.x * v2.x + v2.y * v2.y + v2.z * v2.z + v2.w * v2.w;
        a3 += v3.x * v3.x + v3.y * v3.y + v3.z * v3.z + v3.w * v3.w;
    }
    return (a0 + a1) + (a2 + a3);
}

__device__ __forceinline__ void produce(const float* __restrict__ in,
                                        float* __restrict__ sumsq,
                                        unsigned int* __restrict__ cnt,
                                        int s, int tid, int lane, int wave,
                                        float* red)
{
    float acc = slice_sumsq(in, s, tid);
    for (int off = 32; off > 0; off >>= 1)
        acc += __shfl_down(acc, off, 64);
    if (lane == 0) red[wave] = acc;
    __syncthreads();
    if (tid == 0) {
        float tot = red[0] + red[1] + red[2] + red[3];
        __hip_atomic_store(&sumsq[s], tot, __ATOMIC_RELAXED,
                           __HIP_MEMORY_SCOPE_AGENT);
        __hip_atomic_fetch_add(&cnt[s >> 8], 1u, __ATOMIC_RELEASE,
                               __HIP_MEMORY_SCOPE_AGENT);
    }
    __syncthreads();   // red[] reused by next produce
}

__device__ __forceinline__ float gate_for(const float* __restrict__ sumsq,
                                          const unsigned int* __restrict__ cnt,
                                          const float* __restrict__ w_down,
                                          const float* __restrict__ b_down,
                                          const float* __restrict__ w_up,
                                          const float* __restrict__ b_up,
                                          int b, int c, int tid,
                                          float* xs, float* hs, float* gsh)
{
    if (tid == 0) {
        while (__hip_atomic_load(&cnt[b], __ATOMIC_ACQUIRE,
                                 __HIP_MEMORY_SCOPE_AGENT) < (unsigned)CC)
            __builtin_amdgcn_s_sleep(8);
    }
    __syncthreads();

    // x[k] for all 256 channels of batch b (agent-scope loads: coherent)
    {
        float ss = __hip_atomic_load(&sumsq[(b << 8) + tid], __ATOMIC_RELAXED,
                                     __HIP_MEMORY_SCOPE_AGENT);
        float g = sqrtf(ss);
        xs[tid] = g / (g + 1e-6f);
    }
    __syncthreads();

    // h[j] = relu(b_down[j] + sum_k x[k] * w_down[j][k]); 16 threads per j
    {
        const int j = tid >> 4, l = tid & 15;
        const float* wr = w_down + j * CC;
        float a = 0.f;
        #pragma unroll
        for (int k = 0; k < CC / 16; ++k)
            a += xs[l + k * 16] * wr[l + k * 16];
        a += __shfl_down(a, 8, 16);
        a += __shfl_down(a, 4, 16);
        a += __shfl_down(a, 2, 16);
        a += __shfl_down(a, 1, 16);
        if (l == 0) hs[j] = fmaxf(a + b_down[j], 0.f);
    }
    __syncthreads();

    if (tid == 0) {
        float a = b_up[c];
        const float* wu = w_up + c * INTERNAL;
        #pragma unroll
        for (int j = 0; j < INTERNAL; ++j) a += hs[j] * wu[j];
        *gsh = 1.f / (1.f + expf(-a));
    }
    __syncthreads();
    return *gsh;
}

__device__ __forceinline__ void scale_store(const float* __restrict__ in,
                                            float* __restrict__ out,
                                            float gv, int s, int tid)
{
    const f4* pi = reinterpret_cast<const f4*>(in + (size_t)s * HWSZ);
    f4* po = reinterpret_cast<f4*>(out + (size_t)s * HWSZ);
    #pragma unroll
    for (int i = 0; i < IT; i += 4) {
        f4 v0 = __builtin_nontemporal_load(pi + tid + (i + 0) * TPB);
        f4 v1 = __builtin_nontemporal_load(pi + tid + (i + 1) * TPB);
        f4 v2 = __builtin_nontemporal_load(pi + tid + (i + 2) * TPB);
        f4 v3 = __builtin_nontemporal_load(pi + tid + (i + 3) * TPB);
        v0 *= gv; v1 *= gv; v2 *= gv; v3 *= gv;
        __builtin_nontemporal_store(v0, po + tid + (i + 0) * TPB);
        __builtin_nontemporal_store(v1, po + tid + (i + 1) * TPB);
        __builtin_nontemporal_store(v2, po + tid + (i + 2) * TPB);
        __builtin_nontemporal_store(v3, po + tid + (i + 3) * TPB);
    }
}

// ---------------- single-kernel pipelined version ----------------
// Cooperative launch guarantees all 1024 blocks co-resident (4/CU needed,
// VGPR<=128, LDS ~1.2KB -> plenty of margin), so per-batch atomic spin
// barriers cannot deadlock. No grid.sync (R5: ~160us each).
__global__ __launch_bounds__(TPB, 4) void se_onepass_kernel(
    const float* __restrict__ in, float* __restrict__ out,
    float* __restrict__ sumsq,          // [NSLICE]
    unsigned int* __restrict__ cnt,     // [BB], zeroed per call
    const float* __restrict__ w_down, const float* __restrict__ b_down,
    const float* __restrict__ w_up, const float* __restrict__ b_up)
{
    const int blk = blockIdx.x;
    const int tid = threadIdx.x;
    const int lane = tid & 63, wave = tid >> 6;

    __shared__ float red[4];
    __shared__ float xs[CC];
    __shared__ float hs[INTERNAL];
    __shared__ float gsh;

    const int sA = blk;          // batch 0..3
    const int sB = blk + NBLK;   // batch 4..7

    // phase 1: both slices' sum of squares (caching loads)
    produce(in, sumsq, cnt, sA, tid, lane, wave, red);
    produce(in, sumsq, cnt, sB, tid, lane, wave, red);

    // phase 2+3 for slice A (its lines are L3-hot; scale streams while
    // other blocks still produce batch B partials)
    float gA = gate_for(sumsq, cnt, w_down, b_down, w_up, b_up,
                        sA >> 8, sA & 255, tid, xs, hs, &gsh);
    scale_store(in, out, gA, sA, tid);

    // phase 2+3 for slice B
    float gB = gate_for(sumsq, cnt, w_down, b_down, w_up, b_up,
                        sB >> 8, sB & 255, tid, xs, hs, &gsh);
    scale_store(in, out, gB, sB, tid);
}

// ---------------- fallback: proven R7 two-kernel path (144 us) ----------
__global__ __launch_bounds__(TPB) void se_sumsq_kernel(
    const float* __restrict__ in, float* __restrict__ sumsq)
{
    const int bc = blockIdx.x;
    float acc = slice_sumsq(in, bc, threadIdx.x);
    for (int off = 32; off > 0; off >>= 1)
        acc += __shfl_down(acc, off, 64);
    __shared__ float red[4];
    const int lane = threadIdx.x & 63, wave = threadIdx.x >> 6;
    if (lane == 0) red[wave] = acc;
    __syncthreads();
    if (threadIdx.x == 0)
        sumsq[bc] = red[0] + red[1] + red[2] + red[3];
}

__global__ __launch_bounds__(TPB) void se_scale_kernel(
    const float* __restrict__ in,
    const float* __restrict__ sumsq,
    const float* __restrict__ w_down, const float* __restrict__ b_down,
    const float* __restrict__ w_up, const float* __restrict__ b_up,
    float* __restrict__ out)
{
    const int s = (NSLICE - 1) - blockIdx.x;   // reverse order: LIFO L3 reuse
    const int b = s >> 8;
    const int c = s & 255;
    const int tid = threadIdx.x;

    __shared__ float xs[CC];
    __shared__ float hs[INTERNAL];
    __shared__ float gsh;

    {
        float g = sqrtf(sumsq[(b << 8) + tid]);
        xs[tid] = g / (g + 1e-6f);
    }
    __syncthreads();
    {
        const int j = tid >> 4, l = tid & 15;
        const float* wr = w_down + j * CC;
        float a = 0.f;
        #pragma unroll
        for (int k = 0; k < CC / 16; ++k)
            a += xs[l + k * 16] * wr[l + k * 16];
        a += __shfl_down(a, 8, 16);
        a += __shfl_down(a, 4, 16);
        a += __shfl_down(a, 2, 16);
        a += __shfl_down(a, 1, 16);
        if (l == 0) hs[j] = fmaxf(a + b_down[j], 0.f);
    }
    __syncthreads();
    if (tid == 0) {
        float a = b_up[c];
        const float* wu = w_up + c * INTERNAL;
        #pragma unroll
        for (int j = 0; j < INTERNAL; ++j) a += hs[j] * wu[j];
        gsh = 1.f / (1.f + expf(-a));
    }
    __syncthreads();
    scale_store(in, out, gsh, s, tid);
}

extern "C" void kernel_launch(void* const* d_in, const int* in_sizes, int n_in,
                              void* d_out, int out_size, void* d_ws, size_t ws_size,
                              hipStream_t stream) {
    const float* inputs = (const float*)d_in[0];   // [B, C, H, W]
    const float* w_down = (const float*)d_in[1];   // [16, 256]
    const float* b_down = (const float*)d_in[2];   // [16]
    const float* w_up   = (const float*)d_in[3];   // [256, 16]
    const float* b_up   = (const float*)d_in[4];   // [256]
    float* out = (float*)d_out;

    float* sumsq      = (float*)d_ws;              // 2048 floats
    unsigned int* cnt = (unsigned int*)(sumsq + NSLICE);  // 8 uints

    // zero the per-batch arrival counters every call (replay-safe)
    hipMemsetAsync(cnt, 0, BB * sizeof(unsigned int), stream);

    void* args[] = { (void*)&inputs, (void*)&out, (void*)&sumsq, (void*)&cnt,
                     (void*)&w_down, (void*)&b_down, (void*)&w_up, (void*)&b_up };
    hipError_t err = hipLaunchCooperativeKernel(
        reinterpret_cast<void*>(se_onepass_kernel),
        dim3(NBLK), dim3(TPB), args, 0, stream);

    if (err != hipSuccess) {
        // deterministic fallback: proven R7 two-kernel path
        se_sumsq_kernel<<<NSLICE, TPB, 0, stream>>>(inputs, sumsq);
        se_scale_kernel<<<NSLICE, TPB, 0, stream>>>(inputs, sumsq,
                                                    w_down, b_down, w_up, b_up,
                                                    out);
    }
}

// Round 9
// 144.704 us; speedup vs baseline: 1.9627x; 1.9627x over previous
//
#include <hip/hip_runtime.h>
#include <math.h>

// Problem geometry (fixed by the reference)
#define BB 8
#define CC 256
#define HWSZ 36864            // floats per (b,c) slice
#define TPB 256
#define IT 36                 // float4 per thread per slice (36*256*4 = 36864 floats)
#define INTERNAL 16
#define NSLICE 2048

typedef float f4 __attribute__((ext_vector_type(4)));

// ---- Pass 1: one block per (b,c) slice, full-slice sum of squares ----
// Normal (caching) loads: we WANT the input resident in L3 for pass 3.
__global__ __launch_bounds__(TPB) void se_sumsq_kernel(
    const float* __restrict__ in, float* __restrict__ sumsq)
{
    const int bc = blockIdx.x;
    const f4* p = reinterpret_cast<const f4*>(in + (size_t)bc * HWSZ);

    float a0 = 0.f, a1 = 0.f, a2 = 0.f, a3 = 0.f;
    #pragma unroll
    for (int i = 0; i < IT; i += 4) {
        f4 v0 = p[threadIdx.x + (i + 0) * TPB];
        f4 v1 = p[threadIdx.x + (i + 1) * TPB];
        f4 v2 = p[threadIdx.x + (i + 2) * TPB];
        f4 v3 = p[threadIdx.x + (i + 3) * TPB];
        a0 += v0.x * v0.x + v0.y * v0.y + v0.z * v0.z + v0.w * v0.w;
        a1 += v1.x * v1.x + v1.y * v1.y + v1.z * v1.z + v1.w * v1.w;
        a2 += v2.x * v2.x + v2.y * v2.y + v2.z * v2.z + v2.w * v2.w;
        a3 += v3.x * v3.x + v3.y * v3.y + v3.z * v3.z + v3.w * v3.w;
    }
    float acc = (a0 + a1) + (a2 + a3);
    for (int off = 32; off > 0; off >>= 1)
        acc += __shfl_down(acc, off, 64);

    __shared__ float red[4];
    const int lane = threadIdx.x & 63, wave = threadIdx.x >> 6;
    if (lane == 0) red[wave] = acc;
    __syncthreads();
    if (threadIdx.x == 0)
        sumsq[bc] = red[0] + red[1] + red[2] + red[3];
}

// ---- Pass 2: tiny gate kernel — one block per batch, all 2048 gates ----
// Removes the MLP prologue from the 2048 streaming blocks of pass 3.
__global__ __launch_bounds__(TPB) void se_gate_kernel(
    const float* __restrict__ sumsq,   // [B*C]
    const float* __restrict__ w_down,  // [16, 256]
    const float* __restrict__ b_down,  // [16]
    const float* __restrict__ w_up,    // [256, 16]
    const float* __restrict__ b_up,    // [256]
    float* __restrict__ gate)          // [B*C]
{
    const int b = blockIdx.x;
    const int c = threadIdx.x;

    __shared__ float xs[CC];
    __shared__ float hs[INTERNAL];

    float g = sqrtf(sumsq[(b << 8) + c]);
    xs[c] = g / (g + 1e-6f);
    __syncthreads();

    // h[j] = relu(b_down[j] + sum_k x[k]*w_down[j][k]); 16 threads per j
    {
        const int j = c >> 4, l = c & 15;
        const float* wr = w_down + j * CC;
        float a = 0.f;
        #pragma unroll
        for (int k = 0; k < CC / 16; ++k)
            a += xs[l + k * 16] * wr[l + k * 16];
        a += __shfl_down(a, 8, 16);
        a += __shfl_down(a, 4, 16);
        a += __shfl_down(a, 2, 16);
        a += __shfl_down(a, 1, 16);
        if (l == 0) hs[j] = fmaxf(a + b_down[j], 0.f);
    }
    __syncthreads();

    float a = b_up[c];
    const float* wu = w_up + c * INTERNAL;
    #pragma unroll
    for (int j = 0; j < INTERNAL; ++j) a += hs[j] * wu[j];
    gate[(b << 8) + c] = 1.f / (1.f + expf(-a));
}

// ---- Pass 3: pure streaming scale, REVERSE slice order ----
// Reverse order = LIFO reuse of the input lines pass 1 left in L3.
// nt-loads (input never read again) + nt-stores (output never read)
// preserve the L3-resident input. Prologue is one uniform scalar load.
__global__ __launch_bounds__(TPB) void se_scale_kernel(
    const float* __restrict__ in,
    const float* __restrict__ gate,    // [B*C]
    float* __restrict__ out)
{
    const int s = (NSLICE - 1) - blockIdx.x;   // reverse order
    const int tid = threadIdx.x;
    const float gv = gate[s];

    const f4* pi = reinterpret_cast<const f4*>(in + (size_t)s * HWSZ);
    f4* po = reinterpret_cast<f4*>(out + (size_t)s * HWSZ);

    #pragma unroll
    for (int i = 0; i < IT; i += 4) {
        f4 v0 = __builtin_nontemporal_load(pi + tid + (i + 0) * TPB);
        f4 v1 = __builtin_nontemporal_load(pi + tid + (i + 1) * TPB);
        f4 v2 = __builtin_nontemporal_load(pi + tid + (i + 2) * TPB);
        f4 v3 = __builtin_nontemporal_load(pi + tid + (i + 3) * TPB);
        v0 *= gv; v1 *= gv; v2 *= gv; v3 *= gv;
        __builtin_nontemporal_store(v0, po + tid + (i + 0) * TPB);
        __builtin_nontemporal_store(v1, po + tid + (i + 1) * TPB);
        __builtin_nontemporal_store(v2, po + tid + (i + 2) * TPB);
        __builtin_nontemporal_store(v3, po + tid + (i + 3) * TPB);
    }
}

extern "C" void kernel_launch(void* const* d_in, const int* in_sizes, int n_in,
                              void* d_out, int out_size, void* d_ws, size_t ws_size,
                              hipStream_t stream) {
    const float* inputs = (const float*)d_in[0];   // [B, C, H, W]
    const float* w_down = (const float*)d_in[1];   // [16, 256]
    const float* b_down = (const float*)d_in[2];   // [16]
    const float* w_up   = (const float*)d_in[3];   // [256, 16]
    const float* b_up   = (const float*)d_in[4];   // [256]
    float* out   = (float*)d_out;

    float* sumsq = (float*)d_ws;                   // 2048 floats
    float* gate  = sumsq + NSLICE;                 // 2048 floats

    se_sumsq_kernel<<<NSLICE, TPB, 0, stream>>>(inputs, sumsq);
    se_gate_kernel<<<BB, TPB, 0, stream>>>(sumsq, w_down, b_down,
                                           w_up, b_up, gate);
    se_scale_kernel<<<NSLICE, TPB, 0, stream>>>(inputs, gate, out);
}